// Round 5
// baseline (303.389 us; speedup 1.0000x reference)
//
#include <hip/hip_runtime.h>
#include <stdint.h>
#include <stddef.h>

typedef __attribute__((ext_vector_type(8))) short short8;
typedef __attribute__((ext_vector_type(4))) float f32x4;
typedef __attribute__((ext_vector_type(16))) float f32x16;
typedef __attribute__((ext_vector_type(4))) uint32_t u32x4;

// async global->LDS 16B (wave-uniform base + lane*16 dest; per-lane source)
#define GLD_LDS16(gsrc, ldst)                                                   \
    __builtin_amdgcn_global_load_lds(                                           \
        (const __attribute__((address_space(1))) uint32_t*)(const void*)(gsrc), \
        (__attribute__((address_space(3))) uint32_t*)(void*)(ldst), 16, 0, 0)

static __device__ __forceinline__ uint16_t bf16_rne(float f) {
    uint32_t u = __float_as_uint(f);
    uint32_t r = u + 0x7FFFu + ((u >> 16) & 1u);
    return (uint16_t)(r >> 16);
}
static __device__ __forceinline__ float bf16_f(uint16_t h) {
    return __uint_as_float(((uint32_t)h) << 16);
}

// ---------------- workspace layout (bytes) ----------------
#define OFF_MASKS 0u
#define SZ_MASKS  (2048u * 4096u * 2u)
#define OFF_WIN   (OFF_MASKS + SZ_MASKS)
#define SZ_WIN1   (256u * 4096u * 2u)
#define OFF_WREC  (OFF_WIN + 3u * SZ_WIN1)
#define SZ_WREC1  (256u * 256u * 2u)
#define OFF_WOUT  (OFF_WREC + 2u * SZ_WREC1)
#define SZ_WOUT1  (16u * 256u * 2u)
#define OFF_IIN   (OFF_WOUT + 2u * SZ_WOUT1)

// ---------------- kernel 1: encoder -> 10-bit spike masks ----------------
__global__ __launch_bounds__(256) void k_prep(const float* __restrict__ x,
                                              uint16_t* __restrict__ masks) {
    int g = blockIdx.x * 256 + threadIdx.x;
    int b = g >> 11, s = g & 2047;
    float q = 50.0f * x[g];
    float c = fabsf(q);
    float v = 0.0f;
    uint32_t m = 0u;
    #pragma unroll
    for (int t = 0; t < 10; ++t) {
        v = v + 0.1f * ((0.0f - v) + c);
        if (v > 1.0f) { m |= (1u << t); v = 0.0f; }
    }
    masks[(size_t)b * 4096 + s]        = (q > 0.0f) ? (uint16_t)m : (uint16_t)0;
    masks[(size_t)b * 4096 + 2048 + s] = (q < 0.0f) ? (uint16_t)m : (uint16_t)0;
}

// ---------------- kernel 2: f32 -> bf16 split weights ----------------
__global__ __launch_bounds__(256) void k_wsplit(const float* __restrict__ win,
                                                const float* __restrict__ wrec,
                                                const float* __restrict__ wout,
                                                uint16_t* __restrict__ win_s,
                                                uint16_t* __restrict__ wrec_s,
                                                uint16_t* __restrict__ wout_s) {
    int g = blockIdx.x * 256 + threadIdx.x;
    if (g < 1048576) {
        float w = win[g];
        uint16_t h = bf16_rne(w);
        float r1 = w - bf16_f(h);
        uint16_t md = bf16_rne(r1);
        float r2 = r1 - bf16_f(md);
        win_s[g]            = h;
        win_s[1048576 + g]  = md;
        win_s[2097152 + g]  = bf16_rne(r2);
    } else if (g < 1114112) {
        int i = g - 1048576;
        float w = wrec[i];
        uint16_t h = bf16_rne(w);
        float r1 = w - bf16_f(h);
        wrec_s[i]         = h;
        wrec_s[65536 + i] = bf16_rne(r1);
    } else if (g < 1118208) {
        int i = g - 1114112;
        float w = wout[i];
        uint16_t h = bf16_rne(w);
        float r1 = w - bf16_f(h);
        wout_s[i]        = h;
        wout_s[4096 + i] = bf16_rne(r1);
    }
}

// ---------------- kernel 3: I_in = enc @ w_in.T (binary-A split GEMM) -------
// M=20480, K=4096, N=256. BM=64, BN=128 -> 640 blocks (~2.5/CU, 3 co-resident
// by LDS). 32x32x16 MFMA; A expanded from bit-masks DIRECTLY INTO REGISTERS
// (no Abuf, no A ds-traffic); B: 3-slot 16KB ring, counted vmcnt, 1 barrier
// per phase. Masks for kk+1 issued at s1, retired by s2's vmcnt(4).
__global__ __launch_bounds__(256, 3) void k_gemm(const uint16_t* __restrict__ masks,
                                                 const uint16_t* __restrict__ wsp,
                                                 float* __restrict__ iin) {
    __shared__ uint16_t Bbuf[3][128 * 64];   // 16 KB x3 ring, 48 KB total
    const int tid = threadIdx.x;
    const int lane = tid & 63;
    const int wid = tid >> 6;
    const int l31 = lane & 31;
    const int hi  = lane >> 5;
    const int Mtile = blockIdx.x >> 1;
    const int Ntile = blockIdx.x & 1;
    const int M0 = Mtile * 64;

    // per-thread A meta: 2 m-frags, row = M0 + mf*32 + l31
    uint32_t bb[2], tt[2];
    #pragma unroll
    for (int mf = 0; mf < 2; ++mf) {
        uint32_t m = (uint32_t)(M0 + mf * 32 + l31);
        uint32_t b = (m * 52429u) >> 19;        // m/10
        bb[mf] = b;
        tt[mf] = m - b * 10u;
    }

    u32x4 mq[2][4];                 // staged mask words for kk+1
    auto loadMasks = [&](int kk) {  // 8 x 16B loads per thread
        #pragma unroll
        for (int mf = 0; mf < 2; ++mf) {
            const uint16_t* mp = masks + (size_t)bb[mf] * 4096 + (size_t)(kk * 64 + hi * 8);
            #pragma unroll
            for (int ks = 0; ks < 4; ++ks)
                mq[mf][ks] = *(const u32x4*)(mp + ks * 16);
        }
    };

    short8 af[2][4];                // A frags for current kk (row l31, k = ks*16+hi*8+j)
    auto expand = [&]() {           // pure VALU: bit t -> bf16 {0,1}
        #pragma unroll
        for (int mf = 0; mf < 2; ++mf)
            #pragma unroll
            for (int ks = 0; ks < 4; ++ks) {
                u32x4 o;
                #pragma unroll
                for (int w = 0; w < 4; ++w) {
                    uint32_t x = mq[mf][ks][w] >> tt[mf];
                    o[w] = (x & 0x10001u) * 0x3F80u;   // lo bit0 + hi bit16 -> bf16 1.0s
                }
                af[mf][ks] = *(short8*)&o;
            }
    };

    auto stageB = [&](int kk, int s, uint16_t* bufp) {
        const char* src = (const char*)wsp + (size_t)s * 2097152u;
        char* dst = (char*)bufp;
        #pragma unroll
        for (int p = 0; p < 4; ++p) {
            int c = (p << 8) + tid;                 // 1024 chunks of 16B
            int n = c >> 3;
            uint32_t off = (uint32_t)((c & 7) << 4);
            uint32_t so = (uint32_t)(Ntile * 128 + n) * 8192u + (uint32_t)(kk << 7)
                        + (off ^ (uint32_t)((n & 7) << 4));
            GLD_LDS16(src + so, dst + (size_t)c * 16u);
        }
    };

    f32x16 acc[2];
    #pragma unroll
    for (int mf = 0; mf < 2; ++mf)
        #pragma unroll
        for (int q = 0; q < 16; ++q) acc[mf][q] = 0.0f;

    auto mfmaPhase = [&](const uint16_t* Bp) {
        short8 bf[4];
        const int n = (wid << 5) + l31;
        #pragma unroll
        for (int ks = 0; ks < 4; ++ks) {
            uint32_t byte = (uint32_t)(n * 128)
                          + ((uint32_t)((ks << 5) + (hi << 4)) ^ (uint32_t)((n & 7) << 4));
            bf[ks] = *(const short8*)((const char*)Bp + byte);
        }
        __builtin_amdgcn_s_setprio(1);
        #pragma unroll
        for (int ks = 0; ks < 4; ++ks)
            #pragma unroll
            for (int mf = 0; mf < 2; ++mf)
                acc[mf] = __builtin_amdgcn_mfma_f32_32x32x16_bf16(
                    af[mf][ks], bf[ks], acc[mf], 0, 0, 0);
        __builtin_amdgcn_s_setprio(0);
    };

    // prologue: masks(0)+expand, B(kk=0,s=0) -> slot0 stays in flight
    loadMasks(0);
    stageB(0, 0, Bbuf[0]);
    asm volatile("s_waitcnt vmcnt(4)" ::: "memory");   // masks done; slot0 in flight
    expand();

    #pragma unroll 1
    for (int kk = 0; kk < 64; ++kk) {
        const bool more = (kk < 63);
        // ---- s0: reads slot0; stages slot1 ----
        stageB(kk, 1, Bbuf[1]);
        asm volatile("s_waitcnt vmcnt(4)" ::: "memory");   // retire slot0
        __builtin_amdgcn_s_barrier();
        __builtin_amdgcn_sched_barrier(0);
        mfmaPhase(Bbuf[0]);
        // ---- s1: reads slot1; stages slot2; issue masks(kk+1) ----
        stageB(kk, 2, Bbuf[2]);
        if (more) {
            loadMasks(kk + 1);
            asm volatile("s_waitcnt vmcnt(12)" ::: "memory");  // retire slot1, keep slot2+masks
        } else {
            asm volatile("s_waitcnt vmcnt(4)" ::: "memory");   // retire slot1, keep slot2
        }
        __builtin_amdgcn_s_barrier();
        __builtin_amdgcn_sched_barrier(0);
        mfmaPhase(Bbuf[1]);
        // ---- s2: reads slot2; stages slot0 for kk+1; retire masks ----
        if (more) {
            stageB(kk + 1, 0, Bbuf[0]);
            asm volatile("s_waitcnt vmcnt(4)" ::: "memory");   // retire slot2+masks, keep slot0'
        } else {
            asm volatile("s_waitcnt vmcnt(0)" ::: "memory");
        }
        __builtin_amdgcn_s_barrier();
        __builtin_amdgcn_sched_barrier(0);
        mfmaPhase(Bbuf[2]);
        if (more) expand();                                    // af <- masks(kk+1)
    }

    // C store: 32x32 layout: col = l31, row = (r&3) + 8*(r>>2) + 4*hi
    #pragma unroll
    for (int mf = 0; mf < 2; ++mf)
        #pragma unroll
        for (int r = 0; r < 16; ++r) {
            int row = (r & 3) + ((r >> 2) << 3) + (hi << 2);
            int gm = M0 + mf * 32 + row;
            int h = Ntile * 128 + (wid << 5) + l31;
            iin[(size_t)gm * 256 + h] = acc[mf][r];
        }
}

// ---------------- kernel 4: recurrent scan + LI readout + softmax ----------
// 256 blocks x 8 batch rows -> every CU busy. w_rec streamed as 64KB
// [256 n][128 k] double-buffered slots (4 phases per t). z_new kept in regs
// during the j-loop; Z single-buffered (16-row frame, rows 8-15 always 0).
__global__ __launch_bounds__(256) void k_scan(const float* __restrict__ iin,
                                              const uint16_t* __restrict__ wrec_s,
                                              const uint16_t* __restrict__ wout_s,
                                              float* __restrict__ out) {
    __shared__ uint16_t Bb[2][256 * 128];   // 128 KB ring of w_rec half-split tiles
    __shared__ uint16_t Zb[16 * 256];       // 8 KB z spikes (rows 8-15 stay 0)
    __shared__ uint16_t WO[2][16 * 256];    // 16 KB resident w_out splits
    const int tid = threadIdx.x;
    const int lane = tid & 63;
    const int wid = tid >> 6;
    const int l15 = lane & 15;
    const int lq = lane >> 4;
    const int b0 = blockIdx.x << 3;          // 8 rows per block

    auto stageBrec = [&](int g, int db) {    // g = t*4 + j; tile = (sp, kh)
        int sp = (g >> 1) & 1;
        int kh = g & 1;
        const char* src = (const char*)wrec_s + (size_t)sp * 131072u;
        char* dst = (char*)Bb[db];
        #pragma unroll
        for (int p = 0; p < 16; ++p) {
            int c = (p << 8) + tid;              // 4096 chunks of 16B
            int n = c >> 4;
            uint32_t x0 = (uint32_t)((c & 15) << 4);
            uint32_t so = (uint32_t)(n * 512) + (uint32_t)(kh << 8)
                        + (x0 ^ (uint32_t)((n & 7) << 4));
            GLD_LDS16(src + so, dst + (size_t)c * 16);
        }
    };

    stageBrec(0, 0);                         // 16 loads in flight

    // stage w_out splits (swizzled rows of 512B)
    #pragma unroll
    for (int s = 0; s < 2; ++s) {
        #pragma unroll
        for (int p = 0; p < 2; ++p) {
            int c = (p << 8) + tid;
            int n = c >> 5;
            uint32_t off = (uint32_t)((c & 31) << 4);
            u32x4 v = *(const u32x4*)((const char*)(wout_s + (size_t)s * 4096) + (size_t)n * 512 + off);
            *(u32x4*)((char*)WO[s] + (uint32_t)(n * 512) + (off ^ (uint32_t)((n & 7) << 4))) = v;
        }
    }
    // Z = 0 (all 16 rows)
    #pragma unroll
    for (int p = 0; p < 8; ++p) ((uint32_t*)Zb)[(p << 8) + tid] = 0u;

    asm volatile("s_waitcnt lgkmcnt(0)" ::: "memory");   // ds writes visible; vmem stays
    __builtin_amdgcn_s_barrier();

    // state: thread holds (brow = lq*4+r, h = wid*64 + nf*16 + l15); brow<8 real
    float vst[4][4], ist[4][4];
    #pragma unroll
    for (int nf = 0; nf < 4; ++nf)
        #pragma unroll
        for (int r = 0; r < 4; ++r) { vst[nf][r] = 0.0f; ist[nf][r] = 0.0f; }
    float io_[4] = {0.f, 0.f, 0.f, 0.f};
    float vo_[4] = {0.f, 0.f, 0.f, 0.f};
    float mm[4] = {-1e30f, -1e30f, -1e30f, -1e30f};

    #pragma unroll 1
    for (int t = 0; t < 10; ++t) {
        f32x4 acc[4];
        uint32_t zb[4];                      // z_new bits, written to Zb after j-loop
        #pragma unroll
        for (int nf = 0; nf < 4; ++nf) {
            zb[nf] = 0u;
            #pragma unroll
            for (int r = 0; r < 4; ++r) {
                int brow = (lq << 2) + r;
                float vv = vst[nf][r];
                float ii = ist[nf][r];
                float vd = vv + 0.1f * ((0.0f - vv) + ii);
                bool z = (vd > 1.0f);
                vst[nf][r] = z ? 0.0f : vd;
                if (z) zb[nf] |= (1u << r);
                int h = (wid << 6) + (nf << 4) + l15;
                int rowc = brow < 8 ? brow : 7;
                float I = iin[(size_t)((b0 + rowc) * 10 + t) * 256 + h];
                I = (brow < 8) ? I : 0.0f;
                acc[nf][r] = 0.8f * ii + I;
            }
        }
        // i += z_old @ w_rec.T : 4 phases of [256 n][128 k] (2 splits x 2 halves)
        for (int j = 0; j < 4; ++j) {
            int g = (t << 2) + j;
            int kh = g & 1;
            __builtin_amdgcn_s_barrier();            // prior readers of slot (g+1)&1 done
            if (g + 1 < 40) {
                stageBrec(g + 1, (g + 1) & 1);
                asm volatile("s_waitcnt vmcnt(16)" ::: "memory");   // retire slot g&1
            } else {
                asm volatile("s_waitcnt vmcnt(0)" ::: "memory");
            }
            __builtin_amdgcn_s_barrier();
            __builtin_amdgcn_sched_barrier(0);
            short8 az[4];
            #pragma unroll
            for (int kt = 0; kt < 4; ++kt) {
                uint32_t byte = (uint32_t)(l15 * 512)
                              + ((uint32_t)((kh << 8) + (kt << 6) + (lq << 4))
                                 ^ (uint32_t)((l15 & 7) << 4));
                az[kt] = *(const short8*)((const char*)Zb + byte);
            }
            const char* Bp = (const char*)Bb[g & 1];
            __builtin_amdgcn_s_setprio(1);
            #pragma unroll
            for (int nf = 0; nf < 4; ++nf) {
                int n = (wid << 6) + (nf << 4) + l15;
                #pragma unroll
                for (int kt = 0; kt < 4; ++kt) {
                    uint32_t byte = (uint32_t)(n * 256)
                                  + ((uint32_t)((kt << 6) + (lq << 4)) ^ (uint32_t)((n & 7) << 4));
                    short8 bw = *(const short8*)(Bp + byte);
                    acc[nf] = __builtin_amdgcn_mfma_f32_16x16x32_bf16(az[kt], bw, acc[nf], 0, 0, 0);
                }
            }
            __builtin_amdgcn_s_setprio(0);
        }
        #pragma unroll
        for (int nf = 0; nf < 4; ++nf)
            #pragma unroll
            for (int r = 0; r < 4; ++r) ist[nf][r] = acc[nf][r];

        // publish z_t to Zb (rows < 8 only; rows 8-15 stay 0)
        __builtin_amdgcn_s_barrier();
        #pragma unroll
        for (int nf = 0; nf < 4; ++nf)
            #pragma unroll
            for (int r = 0; r < 4; ++r) {
                int brow = (lq << 2) + r;
                if (brow < 8) {
                    int h = (wid << 6) + (nf << 4) + l15;
                    uint32_t byte = (uint32_t)(brow * 512)
                                  + ((uint32_t)(h << 1) ^ (uint32_t)((brow & 7) << 4));
                    *(uint16_t*)((char*)Zb + byte) =
                        ((zb[nf] >> r) & 1u) ? (uint16_t)0x3F80u : (uint16_t)0u;
                }
            }
        asm volatile("s_waitcnt lgkmcnt(0)" ::: "memory");
        __builtin_amdgcn_s_barrier();

        // LI readout on wave 0: io_new = 0.8*io + z_t @ w_out.T ; vo uses OLD io
        if (wid == 0) {
            f32x4 aio;
            #pragma unroll
            for (int r = 0; r < 4; ++r) aio[r] = 0.8f * io_[r];
            #pragma unroll
            for (int s = 0; s < 2; ++s) {
                #pragma unroll
                for (int kc = 0; kc < 8; ++kc) {
                    int kb = (kc << 6) + (lq << 4);
                    uint32_t byte = (uint32_t)(l15 * 512)
                                  + ((uint32_t)kb ^ (uint32_t)((l15 & 7) << 4));
                    short8 azn = *(const short8*)((const char*)Zb + byte);
                    short8 bwo = *(const short8*)((const char*)WO[s] + byte);
                    aio = __builtin_amdgcn_mfma_f32_16x16x32_bf16(azn, bwo, aio, 0, 0, 0);
                }
            }
            #pragma unroll
            for (int r = 0; r < 4; ++r) {
                float von = vo_[r] + 0.1f * ((0.0f - vo_[r]) + io_[r]);
                io_[r] = aio[r];
                vo_[r] = von;
                mm[r] = fmaxf(mm[r], von);
            }
        }
    }

    // fused: m = max_t(vo); nan->0; softmax over A=16 (16-lane groups)
    if (wid == 0 && lq < 2) {
        #pragma unroll
        for (int r = 0; r < 4; ++r) {
            float mv = mm[r];
            if (mv != mv) mv = 0.0f;
            float mx = mv;
            #pragma unroll
            for (int d = 1; d < 16; d <<= 1) mx = fmaxf(mx, __shfl_xor(mx, d));
            float e = __expf(mv - mx);
            float ss = e;
            #pragma unroll
            for (int d = 1; d < 16; d <<= 1) ss += __shfl_xor(ss, d);
            out[(size_t)(b0 + (lq << 2) + r) * 16 + l15] = e / ss;
        }
    }
}

extern "C" void kernel_launch(void* const* d_in, const int* in_sizes, int n_in,
                              void* d_out, int out_size, void* d_ws, size_t ws_size,
                              hipStream_t stream) {
    (void)in_sizes; (void)n_in; (void)out_size; (void)ws_size;
    const float* x     = (const float*)d_in[0];
    const float* w_in  = (const float*)d_in[1];
    const float* w_rec = (const float*)d_in[2];
    const float* w_out = (const float*)d_in[3];
    float* out = (float*)d_out;
    char* ws = (char*)d_ws;
    uint16_t* masks  = (uint16_t*)(ws + OFF_MASKS);
    uint16_t* win_s  = (uint16_t*)(ws + OFF_WIN);
    uint16_t* wrec_s = (uint16_t*)(ws + OFF_WREC);
    uint16_t* wout_s = (uint16_t*)(ws + OFF_WOUT);
    float* iin = (float*)(ws + OFF_IIN);

    k_prep  <<<dim3(16384), dim3(256), 0, stream>>>(x, masks);
    k_wsplit<<<dim3(4368),  dim3(256), 0, stream>>>(w_in, w_rec, w_out, win_s, wrec_s, wout_s);
    k_gemm  <<<dim3(640),   dim3(256), 0, stream>>>(masks, win_s, iin);
    k_scan  <<<dim3(256),   dim3(256), 0, stream>>>(iin, wrec_s, wout_s, out);
}

// Round 7
// 259.709 us; speedup vs baseline: 1.1682x; 1.1682x over previous
//
#include <hip/hip_runtime.h>
#include <stdint.h>
#include <stddef.h>

typedef __attribute__((ext_vector_type(8))) short short8;
typedef __attribute__((ext_vector_type(4))) float f32x4;
typedef __attribute__((ext_vector_type(4))) uint32_t u32x4;

// async global->LDS 16B (wave-uniform base + lane*16 dest; per-lane source)
#define GLD_LDS16(gsrc, ldst)                                                   \
    __builtin_amdgcn_global_load_lds(                                           \
        (const __attribute__((address_space(1))) uint32_t*)(const void*)(gsrc), \
        (__attribute__((address_space(3))) uint32_t*)(void*)(ldst), 16, 0, 0)

static __device__ __forceinline__ uint16_t bf16_rne(float f) {
    uint32_t u = __float_as_uint(f);
    uint32_t r = u + 0x7FFFu + ((u >> 16) & 1u);
    return (uint16_t)(r >> 16);
}
static __device__ __forceinline__ float bf16_f(uint16_t h) {
    return __uint_as_float(((uint32_t)h) << 16);
}

// ---------------- workspace layout (bytes) ----------------
#define OFF_MASKS 0u
#define SZ_MASKS  (2048u * 4096u * 2u)
#define OFF_WIN   (OFF_MASKS + SZ_MASKS)
#define SZ_WIN1   (256u * 4096u * 2u)
#define OFF_WREC  (OFF_WIN + 3u * SZ_WIN1)
#define SZ_WREC1  (256u * 256u * 2u)
#define OFF_WOUT  (OFF_WREC + 2u * SZ_WREC1)
#define SZ_WOUT1  (16u * 256u * 2u)
#define OFF_IIN   (OFF_WOUT + 2u * SZ_WOUT1)

// ---------------- kernel 1: encoder -> 10-bit spike masks ----------------
__global__ __launch_bounds__(256) void k_prep(const float* __restrict__ x,
                                              uint16_t* __restrict__ masks) {
    int g = blockIdx.x * 256 + threadIdx.x;
    int b = g >> 11, s = g & 2047;
    float q = 50.0f * x[g];
    float c = fabsf(q);
    float v = 0.0f;
    uint32_t m = 0u;
    #pragma unroll
    for (int t = 0; t < 10; ++t) {
        v = v + 0.1f * ((0.0f - v) + c);
        if (v > 1.0f) { m |= (1u << t); v = 0.0f; }
    }
    masks[(size_t)b * 4096 + s]        = (q > 0.0f) ? (uint16_t)m : (uint16_t)0;
    masks[(size_t)b * 4096 + 2048 + s] = (q < 0.0f) ? (uint16_t)m : (uint16_t)0;
}

// ---------------- kernel 2: f32 -> bf16 split weights ----------------
__global__ __launch_bounds__(256) void k_wsplit(const float* __restrict__ win,
                                                const float* __restrict__ wrec,
                                                const float* __restrict__ wout,
                                                uint16_t* __restrict__ win_s,
                                                uint16_t* __restrict__ wrec_s,
                                                uint16_t* __restrict__ wout_s) {
    int g = blockIdx.x * 256 + threadIdx.x;
    if (g < 1048576) {
        float w = win[g];
        uint16_t h = bf16_rne(w);
        float r1 = w - bf16_f(h);
        uint16_t md = bf16_rne(r1);
        float r2 = r1 - bf16_f(md);
        win_s[g]            = h;
        win_s[1048576 + g]  = md;
        win_s[2097152 + g]  = bf16_rne(r2);
    } else if (g < 1114112) {
        int i = g - 1048576;
        float w = wrec[i];
        uint16_t h = bf16_rne(w);
        float r1 = w - bf16_f(h);
        wrec_s[i]         = h;
        wrec_s[65536 + i] = bf16_rne(r1);
    } else if (g < 1118208) {
        int i = g - 1114112;
        float w = wout[i];
        uint16_t h = bf16_rne(w);
        float r1 = w - bf16_f(h);
        wout_s[i]        = h;
        wout_s[4096 + i] = bf16_rne(r1);
    }
}

// ---------------- kernel 3: I_in = enc @ w_in.T (binary-A split GEMM) -------
// M=20480, K=4096, N=256. BM=80, BN=128 -> 512 blocks (2/CU exactly).
// 16x16x32 MFMA (proven conflict-free B-read pattern). A expanded from bit-
// masks DIRECTLY IN REGISTERS (per-lane L2 mask loads; no Abuf, no A ds ops).
// B: 3-slot 16KB ring, counted vmcnt, 1 barrier/phase. LDS 48KB.
__global__ __launch_bounds__(256) void k_gemm(const uint16_t* __restrict__ masks,
                                              const uint16_t* __restrict__ wsp,
                                              float* __restrict__ iin) {
    __shared__ uint16_t Bbuf[3][128 * 64];   // 16 KB x3 ring
    const int tid = threadIdx.x;
    const int lane = tid & 63;
    const int wid = tid >> 6;
    const int l15 = lane & 15;
    const int lq = lane >> 4;
    const int Mtile = blockIdx.x >> 1;
    const int Ntile = blockIdx.x & 1;
    const int M0 = Mtile * 80;

    // per-mt meta: lane's A-row for m-frag mt is M0 + mt*16 + l15
    uint32_t bb[5], tt[5];
    #pragma unroll
    for (int mt = 0; mt < 5; ++mt) {
        uint32_t m = (uint32_t)(M0 + mt * 16 + l15);
        uint32_t b = (m * 52429u) >> 19;        // m/10
        bb[mt] = b;
        tt[mt] = m - b * 10u;
    }

    u32x4 mq[5][2];                  // staged mask words (8 uint16 each)
    auto loadMasks = [&](int kk) {   // lane loads its rows' k-chunks (L2 hits)
        #pragma unroll
        for (int mt = 0; mt < 5; ++mt)
            #pragma unroll
            for (int kt = 0; kt < 2; ++kt)
                mq[mt][kt] = *(const u32x4*)(masks + (size_t)bb[mt] * 4096
                                             + (size_t)(kk * 64 + kt * 32 + lq * 8));
    };

    short8 af[5][2];                 // A frags: row=l15 of frag, k=kt*32+lq*8+j
    auto expand = [&]() {            // pure VALU: bit tt -> bf16 {0,1}
        #pragma unroll
        for (int mt = 0; mt < 5; ++mt)
            #pragma unroll
            for (int kt = 0; kt < 2; ++kt) {
                u32x4 o;
                #pragma unroll
                for (int w = 0; w < 4; ++w) {
                    uint32_t x = mq[mt][kt][w] >> tt[mt];
                    o[w] = (x & 0x10001u) * 0x3F80u;   // lo+hi halves -> bf16 1.0
                }
                af[mt][kt] = *(short8*)&o;
            }
    };

    auto stageB = [&](int kk, int s, uint16_t* bufp) {
        const char* src = (const char*)wsp + (size_t)s * 2097152u;
        char* dst = (char*)bufp;
        #pragma unroll
        for (int p = 0; p < 4; ++p) {
            int c = (p << 8) + tid;                 // 1024 chunks of 16B
            int n = c >> 3;
            uint32_t off = (uint32_t)((c & 7) << 4);
            uint32_t so = (uint32_t)(Ntile * 128 + n) * 8192u + (uint32_t)(kk << 7)
                        + (off ^ (uint32_t)((n & 7) << 4));
            GLD_LDS16(src + so, dst + (size_t)c * 16u);
        }
    };

    f32x4 acc[5][2];
    #pragma unroll
    for (int mt = 0; mt < 5; ++mt)
        #pragma unroll
        for (int nt = 0; nt < 2; ++nt)
            #pragma unroll
            for (int q = 0; q < 4; ++q) acc[mt][nt][q] = 0.0f;

    auto mfmaPhase = [&](const uint16_t* Bpp) {     // Round-4 proven B pattern
        short8 bf[2][2];
        #pragma unroll
        for (int nt = 0; nt < 2; ++nt)
            #pragma unroll
            for (int kt = 0; kt < 2; ++kt) {
                int n = (wid << 5) + nt * 16 + l15;
                uint32_t byte = (uint32_t)(n * 128)
                              + ((uint32_t)((kt << 6) + (lq << 4)) ^ (uint32_t)((n & 7) << 4));
                bf[nt][kt] = *(const short8*)((const char*)Bpp + byte);
            }
        __builtin_amdgcn_s_setprio(1);
        #pragma unroll
        for (int kt = 0; kt < 2; ++kt)
            #pragma unroll
            for (int mt = 0; mt < 5; ++mt)
                #pragma unroll
                for (int nt = 0; nt < 2; ++nt)
                    acc[mt][nt] = __builtin_amdgcn_mfma_f32_16x16x32_bf16(
                        af[mt][kt], bf[nt][kt], acc[mt][nt], 0, 0, 0);
        __builtin_amdgcn_s_setprio(0);
    };

    // prologue: masks(0) (10 loads) then slot0 stage (4) -> vmcnt(4) keeps slot0
    loadMasks(0);
    stageB(0, 0, Bbuf[0]);
    asm volatile("s_waitcnt vmcnt(4)" ::: "memory");
    expand();

    #pragma unroll 1
    for (int kk = 0; kk < 64; ++kk) {
        const bool more = (kk < 63);
        // ---- s0: reads slot0; stages slot1 ----
        stageB(kk, 1, Bbuf[1]);
        asm volatile("s_waitcnt vmcnt(4)" ::: "memory");       // retire slot0
        __builtin_amdgcn_s_barrier();
        __builtin_amdgcn_sched_barrier(0);
        mfmaPhase(Bbuf[0]);
        // ---- s1: reads slot1; stages slot2; issue masks(kk+1) ----
        stageB(kk, 2, Bbuf[2]);
        if (more) {
            loadMasks(kk + 1);
            asm volatile("s_waitcnt vmcnt(14)" ::: "memory");  // retire slot1; keep slot2+masks
        } else {
            asm volatile("s_waitcnt vmcnt(4)" ::: "memory");   // retire slot1; keep slot2
        }
        __builtin_amdgcn_s_barrier();
        __builtin_amdgcn_sched_barrier(0);
        mfmaPhase(Bbuf[1]);
        // ---- s2: reads slot2; stages slot0' ; retire slot2+masks ----
        if (more) {
            stageB(kk + 1, 0, Bbuf[0]);
            asm volatile("s_waitcnt vmcnt(4)" ::: "memory");   // retire slot2+masks; keep slot0'
        } else {
            asm volatile("s_waitcnt vmcnt(0)" ::: "memory");
        }
        __builtin_amdgcn_s_barrier();
        __builtin_amdgcn_sched_barrier(0);
        mfmaPhase(Bbuf[2]);
        if (more) expand();                                    // af <- masks(kk+1)
    }

    // C store: col=lane&15, row=(lane>>4)*4+i
    #pragma unroll
    for (int mt = 0; mt < 5; ++mt)
        #pragma unroll
        for (int nt = 0; nt < 2; ++nt)
            #pragma unroll
            for (int i = 0; i < 4; ++i) {
                int gm = M0 + mt * 16 + (lq << 2) + i;
                int h = Ntile * 128 + (wid << 5) + nt * 16 + l15;
                iin[(size_t)gm * 256 + h] = acc[mt][nt][i];
            }
}

// ---------------- kernel 4: recurrent scan + LI readout + softmax ----------
// 256 blocks x 8 batch rows. w_rec streamed as 64KB [256 n][128 k] dbuf slots
// (4 phases per t). z_new kept in regs during j-loop; Z single-buffered.
__global__ __launch_bounds__(256) void k_scan(const float* __restrict__ iin,
                                              const uint16_t* __restrict__ wrec_s,
                                              const uint16_t* __restrict__ wout_s,
                                              float* __restrict__ out) {
    __shared__ uint16_t Bb[2][256 * 128];   // 128 KB ring of w_rec half-split tiles
    __shared__ uint16_t Zb[16 * 256];       // 8 KB z spikes (rows 8-15 stay 0)
    __shared__ uint16_t WO[2][16 * 256];    // 16 KB resident w_out splits
    const int tid = threadIdx.x;
    const int lane = tid & 63;
    const int wid = tid >> 6;
    const int l15 = lane & 15;
    const int lq = lane >> 4;
    const int b0 = blockIdx.x << 3;          // 8 rows per block

    auto stageBrec = [&](int g, int db) {    // g = t*4 + j; tile = (sp, kh)
        int sp = (g >> 1) & 1;
        int kh = g & 1;
        const char* src = (const char*)wrec_s + (size_t)sp * 131072u;
        char* dst = (char*)Bb[db];
        #pragma unroll
        for (int p = 0; p < 16; ++p) {
            int c = (p << 8) + tid;              // 4096 chunks of 16B
            int n = c >> 4;
            uint32_t x0 = (uint32_t)((c & 15) << 4);
            uint32_t so = (uint32_t)(n * 512) + (uint32_t)(kh << 8)
                        + (x0 ^ (uint32_t)((n & 7) << 4));
            GLD_LDS16(src + so, dst + (size_t)c * 16);
        }
    };

    stageBrec(0, 0);                         // 16 loads in flight

    #pragma unroll
    for (int s = 0; s < 2; ++s) {
        #pragma unroll
        for (int p = 0; p < 2; ++p) {
            int c = (p << 8) + tid;
            int n = c >> 5;
            uint32_t off = (uint32_t)((c & 31) << 4);
            u32x4 v = *(const u32x4*)((const char*)(wout_s + (size_t)s * 4096) + (size_t)n * 512 + off);
            *(u32x4*)((char*)WO[s] + (uint32_t)(n * 512) + (off ^ (uint32_t)((n & 7) << 4))) = v;
        }
    }
    #pragma unroll
    for (int p = 0; p < 8; ++p) ((uint32_t*)Zb)[(p << 8) + tid] = 0u;

    asm volatile("s_waitcnt lgkmcnt(0)" ::: "memory");
    __builtin_amdgcn_s_barrier();

    float vst[4][4], ist[4][4];
    #pragma unroll
    for (int nf = 0; nf < 4; ++nf)
        #pragma unroll
        for (int r = 0; r < 4; ++r) { vst[nf][r] = 0.0f; ist[nf][r] = 0.0f; }
    float io_[4] = {0.f, 0.f, 0.f, 0.f};
    float vo_[4] = {0.f, 0.f, 0.f, 0.f};
    float mm[4] = {-1e30f, -1e30f, -1e30f, -1e30f};

    #pragma unroll 1
    for (int t = 0; t < 10; ++t) {
        f32x4 acc[4];
        uint32_t zb[4];
        #pragma unroll
        for (int nf = 0; nf < 4; ++nf) {
            zb[nf] = 0u;
            #pragma unroll
            for (int r = 0; r < 4; ++r) {
                int brow = (lq << 2) + r;
                float vv = vst[nf][r];
                float ii = ist[nf][r];
                float vd = vv + 0.1f * ((0.0f - vv) + ii);
                bool z = (vd > 1.0f);
                vst[nf][r] = z ? 0.0f : vd;
                if (z) zb[nf] |= (1u << r);
                int h = (wid << 6) + (nf << 4) + l15;
                int rowc = brow < 8 ? brow : 7;
                float I = iin[(size_t)((b0 + rowc) * 10 + t) * 256 + h];
                I = (brow < 8) ? I : 0.0f;
                acc[nf][r] = 0.8f * ii + I;
            }
        }
        // i += z_old @ w_rec.T : 4 phases of [256 n][128 k] (2 splits x 2 halves)
        for (int j = 0; j < 4; ++j) {
            int g = (t << 2) + j;
            int kh = g & 1;
            __builtin_amdgcn_s_barrier();
            if (g + 1 < 40) {
                stageBrec(g + 1, (g + 1) & 1);
                asm volatile("s_waitcnt vmcnt(16)" ::: "memory");
            } else {
                asm volatile("s_waitcnt vmcnt(0)" ::: "memory");
            }
            __builtin_amdgcn_s_barrier();
            __builtin_amdgcn_sched_barrier(0);
            short8 az[4];
            #pragma unroll
            for (int kt = 0; kt < 4; ++kt) {
                uint32_t byte = (uint32_t)(l15 * 512)
                              + ((uint32_t)((kh << 8) + (kt << 6) + (lq << 4))
                                 ^ (uint32_t)((l15 & 7) << 4));
                az[kt] = *(const short8*)((const char*)Zb + byte);
            }
            const char* Bp = (const char*)Bb[g & 1];
            __builtin_amdgcn_s_setprio(1);
            #pragma unroll
            for (int nf = 0; nf < 4; ++nf) {
                int n = (wid << 6) + (nf << 4) + l15;
                #pragma unroll
                for (int kt = 0; kt < 4; ++kt) {
                    uint32_t byte = (uint32_t)(n * 256)
                                  + ((uint32_t)((kt << 6) + (lq << 4)) ^ (uint32_t)((n & 7) << 4));
                    short8 bw = *(const short8*)(Bp + byte);
                    acc[nf] = __builtin_amdgcn_mfma_f32_16x16x32_bf16(az[kt], bw, acc[nf], 0, 0, 0);
                }
            }
            __builtin_amdgcn_s_setprio(0);
        }
        #pragma unroll
        for (int nf = 0; nf < 4; ++nf)
            #pragma unroll
            for (int r = 0; r < 4; ++r) ist[nf][r] = acc[nf][r];

        __builtin_amdgcn_s_barrier();
        #pragma unroll
        for (int nf = 0; nf < 4; ++nf)
            #pragma unroll
            for (int r = 0; r < 4; ++r) {
                int brow = (lq << 2) + r;
                if (brow < 8) {
                    int h = (wid << 6) + (nf << 4) + l15;
                    uint32_t byte = (uint32_t)(brow * 512)
                                  + ((uint32_t)(h << 1) ^ (uint32_t)((brow & 7) << 4));
                    *(uint16_t*)((char*)Zb + byte) =
                        ((zb[nf] >> r) & 1u) ? (uint16_t)0x3F80u : (uint16_t)0u;
                }
            }
        asm volatile("s_waitcnt lgkmcnt(0)" ::: "memory");
        __builtin_amdgcn_s_barrier();

        if (wid == 0) {
            f32x4 aio;
            #pragma unroll
            for (int r = 0; r < 4; ++r) aio[r] = 0.8f * io_[r];
            #pragma unroll
            for (int s = 0; s < 2; ++s) {
                #pragma unroll
                for (int kc = 0; kc < 8; ++kc) {
                    int kb = (kc << 6) + (lq << 4);
                    uint32_t byte = (uint32_t)(l15 * 512)
                                  + ((uint32_t)kb ^ (uint32_t)((l15 & 7) << 4));
                    short8 azn = *(const short8*)((const char*)Zb + byte);
                    short8 bwo = *(const short8*)((const char*)WO[s] + byte);
                    aio = __builtin_amdgcn_mfma_f32_16x16x32_bf16(azn, bwo, aio, 0, 0, 0);
                }
            }
            #pragma unroll
            for (int r = 0; r < 4; ++r) {
                float von = vo_[r] + 0.1f * ((0.0f - vo_[r]) + io_[r]);
                io_[r] = aio[r];
                vo_[r] = von;
                mm[r] = fmaxf(mm[r], von);
            }
        }
    }

    if (wid == 0 && lq < 2) {
        #pragma unroll
        for (int r = 0; r < 4; ++r) {
            float mv = mm[r];
            if (mv != mv) mv = 0.0f;
            float mx = mv;
            #pragma unroll
            for (int d = 1; d < 16; d <<= 1) mx = fmaxf(mx, __shfl_xor(mx, d));
            float e = __expf(mv - mx);
            float ss = e;
            #pragma unroll
            for (int d = 1; d < 16; d <<= 1) ss += __shfl_xor(ss, d);
            out[(size_t)(b0 + (lq << 2) + r) * 16 + l15] = e / ss;
        }
    }
}

extern "C" void kernel_launch(void* const* d_in, const int* in_sizes, int n_in,
                              void* d_out, int out_size, void* d_ws, size_t ws_size,
                              hipStream_t stream) {
    (void)in_sizes; (void)n_in; (void)out_size; (void)ws_size;
    const float* x     = (const float*)d_in[0];
    const float* w_in  = (const float*)d_in[1];
    const float* w_rec = (const float*)d_in[2];
    const float* w_out = (const float*)d_in[3];
    float* out = (float*)d_out;
    char* ws = (char*)d_ws;
    uint16_t* masks  = (uint16_t*)(ws + OFF_MASKS);
    uint16_t* win_s  = (uint16_t*)(ws + OFF_WIN);
    uint16_t* wrec_s = (uint16_t*)(ws + OFF_WREC);
    uint16_t* wout_s = (uint16_t*)(ws + OFF_WOUT);
    float* iin = (float*)(ws + OFF_IIN);

    k_prep  <<<dim3(16384), dim3(256), 0, stream>>>(x, masks);
    k_wsplit<<<dim3(4368),  dim3(256), 0, stream>>>(w_in, w_rec, w_out, win_s, wrec_s, wout_s);
    k_gemm  <<<dim3(512),   dim3(256), 0, stream>>>(masks, win_s, iin);
    k_scan  <<<dim3(256),   dim3(256), 0, stream>>>(iin, wrec_s, wout_s, out);
}